// Round 1
// baseline (566.230 us; speedup 1.0000x reference)
//
#include <hip/hip_runtime.h>
#include <math.h>

#define QN   16384
#define CCH  256
#define NCAM 6
#define HFD  32
#define WFD  88
#define DDD  64
#define BEVH 128
#define BEVW 128
#define IMGW 704.0f
#define IMGH 256.0f
#define EPSV 1e-5f

__device__ __forceinline__ float sigmoidf_(float x){ return 1.0f/(1.0f+__expf(-x)); }

// ---------------- feat transpose: (6,256,32,88) -> (6, 32*88, 256) NHWC ----------------
__global__ __launch_bounds__(256) void k_tfeat(const float* __restrict__ feat, float* __restrict__ feat_t){
    __shared__ float tile[32][33];
    int n  = blockIdx.z;
    int pb = blockIdx.x * 32;   // over 2816 pixels
    int cb = blockIdx.y * 32;   // over 256 channels
    int tx = threadIdx.x & 31, ty = threadIdx.x >> 5;
    for (int r = ty; r < 32; r += 8)
        tile[r][tx] = feat[(size_t)(n*256 + cb + r)*2816 + pb + tx];
    __syncthreads();
    for (int r = ty; r < 32; r += 8)
        feat_t[(size_t)(n*2816 + pb + r)*256 + cb + tx] = tile[tx][r];
}

// ---------------- conv weight transpose: (co,ci,kh,kw) -> [kk][ci][co] ----------------
__global__ __launch_bounds__(256) void k_wt(const float* __restrict__ cw, float* __restrict__ wt){
    int idx = blockIdx.x*256 + threadIdx.x;
    if (idx >= 9*256*256) return;
    int co = idx & 255;
    int ci = (idx >> 8) & 255;
    int kk = idx >> 16;
    wt[idx] = cw[(size_t)(co*256 + ci)*9 + kk];
}

// ---------------- per-query geometry: taps + rp ----------------
__global__ __launch_bounds__(256) void k_geom(
    const float* __restrict__ bq, const float* __restrict__ bpos,
    const float* __restrict__ refp, const float* __restrict__ pcr,
    const float* __restrict__ l2i, const float* __restrict__ dpr,
    const float* __restrict__ w_pos, const float* __restrict__ b_pos,
    const float* __restrict__ w_img, const float* __restrict__ b_img,
    const float* __restrict__ w_att, const float* __restrict__ b_att,
    int* __restrict__ tap_off, float* __restrict__ tap_w,
    float* __restrict__ out_rp)
{
    int wave = (blockIdx.x * blockDim.x + threadIdx.x) >> 6;
    int lane = threadIdx.x & 63;
    int q = wave;
    int c0 = lane * 4;

    const float4 a4 = *(const float4*)(bq  + (size_t)q*CCH + c0);
    const float4 b4 = *(const float4*)(bpos+ (size_t)q*CCH + c0);
    float qv[4] = {a4.x+b4.x, a4.y+b4.y, a4.z+b4.z, a4.w+b4.w};

    float s[19];   // 0: pos, 1..6: att, 7..18: img
    {
        const float4 wp = *(const float4*)(w_pos + c0);
        s[0] = qv[0]*wp.x + qv[1]*wp.y + qv[2]*wp.z + qv[3]*wp.w;
    }
    #pragma unroll
    for (int j=0;j<6;j++){
        float a = 0.f;
        #pragma unroll
        for (int k=0;k<4;k++) a += qv[k]*w_att[(c0+k)*6 + j];
        s[1+j] = a;
    }
    #pragma unroll
    for (int j=0;j<12;j++){
        float a = 0.f;
        #pragma unroll
        for (int k=0;k<4;k++) a += qv[k]*w_img[(c0+k)*12 + j];
        s[7+j] = a;
    }
    #pragma unroll
    for (int off=1; off<64; off<<=1){
        #pragma unroll
        for (int i=0;i<19;i++) s[i] += __shfl_xor(s[i], off, 64);
    }

    float pos_off = s[0] + b_pos[0];
    float rx = refp[q*3+0], ry = refp[q*3+1], rz = refp[q*3+2];
    float zc_ = fminf(fmaxf(rz, 0.f), 1.f);
    float inv = logf(fmaxf(zc_, EPSV) / fmaxf(1.f - zc_, EPSV));
    float znew = sigmoidf_(inv + pos_off);

    if (lane == 0){
        out_rp[q*3+0] = rx; out_rp[q*3+1] = ry; out_rp[q*3+2] = znew;
    }
    if (lane < NCAM){
        int n = lane;
        float att  = s[1+n] + b_att[n];
        float offx = (s[7+2*n]   + b_img[2*n])   / (float)WFD;
        float offy = (s[7+2*n+1] + b_img[2*n+1]) / (float)HFD;
        float lo0=pcr[0], lo1=pcr[1], lo2=pcr[2];
        float hi0=pcr[3], hi1=pcr[4], hi2=pcr[5];
        float px = rx*(hi0-lo0)+lo0, py = ry*(hi1-lo1)+lo1, pz = znew*(hi2-lo2)+lo2;
        const float* M = l2i + n*16;
        float cx = M[0]*px + M[1]*py + M[2]*pz  + M[3];
        float cy = M[4]*px + M[5]*py + M[6]*pz  + M[7];
        float cz = M[8]*px + M[9]*py + M[10]*pz + M[11];
        bool m = cz > EPSV;
        float zdiv = fmaxf(cz, EPSV);
        float u = (cx/zdiv)/IMGW; u = (u - 0.5f)*2.f;
        float v = (cy/zdiv)/IMGH; v = (v - 0.5f)*2.f;
        m = m && (u > -1.f) && (u < 1.f) && (v > -1.f) && (v < 1.f);
        float rdn = (cz/(float)DDD - 0.5f)*2.f;
        m = m && (rdn > -1.f) && (rdn < 1.f);

        int base = q*24 + n*4;
        float wq = 0.f, xs = 0.f, ys = 0.f;
        if (m){
            float u2 = u + offx, v2 = v + offy;
            xs = (u2 + 1.f)*0.5f*WFD - 0.5f;
            ys = (v2 + 1.f)*0.5f*HFD - 0.5f;
            float zs = (rdn + 1.f)*0.5f*DDD - 0.5f;
            float fx = floorf(xs), fy = floorf(ys), fz = floorf(zs);
            int x0=(int)fx, y0=(int)fy, z0=(int)fz;
            float wx = xs-fx, wy = ys-fy, wz = zs-fz;
            float dp = 0.f;
            const float* vol = dpr + (size_t)n*DDD*HFD*WFD;
            #pragma unroll
            for (int dz=0; dz<2; dz++)
            #pragma unroll
            for (int dy=0; dy<2; dy++)
            #pragma unroll
            for (int dx=0; dx<2; dx++){
                int ix=x0+dx, iy=y0+dy, iz=z0+dz;
                if (ix>=0 && ix<WFD && iy>=0 && iy<HFD && iz>=0 && iz<DDD){
                    float ww = (dx?wx:1.f-wx)*(dy?wy:1.f-wy)*(dz?wz:1.f-wz);
                    dp += ww * vol[(size_t)(iz*HFD+iy)*WFD + ix];
                }
            }
            wq = sigmoidf_(att) * dp;
        }
        if (m && wq != 0.f){
            float fx = floorf(xs), fy = floorf(ys);
            int x0=(int)fx, y0=(int)fy;
            float wx = xs-fx, wy = ys-fy;
            float cwv[4] = {(1.f-wx)*(1.f-wy), wx*(1.f-wy), (1.f-wx)*wy, wx*wy};
            int xi[4] = {x0, x0+1, x0, x0+1};
            int yi[4] = {y0, y0, y0+1, y0+1};
            #pragma unroll
            for (int k=0;k<4;k++){
                bool ok = (xi[k]>=0 && xi[k]<WFD && yi[k]>=0 && yi[k]<HFD);
                tap_off[base+k] = ok ? ((n*HFD + yi[k])*WFD + xi[k]) : 0;
                tap_w[base+k]   = ok ? wq*cwv[k] : 0.f;
            }
        } else {
            #pragma unroll
            for (int k=0;k<4;k++){ tap_off[base+k] = 0; tap_w[base+k] = 0.f; }
        }
    }
}

// ---------------- aggregation: agg[q][c] = sum_taps w * feat_t[off][c] ----------------
__global__ __launch_bounds__(256) void k_agg(const float* __restrict__ feat_t,
    const int* __restrict__ tap_off, const float* __restrict__ tap_w,
    float* __restrict__ aggN)
{
    __shared__ int   so[24];
    __shared__ float sw[24];
    int q = blockIdx.x;
    int t = threadIdx.x;
    if (t < 24){ so[t] = tap_off[q*24+t]; sw[t] = tap_w[q*24+t]; }
    __syncthreads();
    float acc = 0.f;
    #pragma unroll
    for (int k=0;k<24;k++){
        float w = sw[k];
        if (w != 0.f) acc += w * feat_t[(size_t)so[k]*CCH + t];
    }
    aggN[(size_t)q*CCH + t] = acc;
}

// ---------------- conv3x3 256->256 + bias + BN + ReLU, NHWC ----------------
__global__ __launch_bounds__(256) void k_conv(const float* __restrict__ aggN,
    const float* __restrict__ wt, const float* __restrict__ conv_b,
    const float* __restrict__ bn_g, const float* __restrict__ bn_b,
    const float* __restrict__ bn_m, const float* __restrict__ bn_v,
    float* __restrict__ xN)
{
    __shared__ float in_lds[32][36];   // [ci][px], 16B-aligned rows
    __shared__ float w_lds[32*128];    // [ci][co]
    int strip = blockIdx.x;            // 0..511: h = strip/4, w0 = (strip%4)*32
    int co0   = blockIdx.y * 128;
    int h  = strip >> 2;
    int w0 = (strip & 3) * 32;
    int tid = threadIdx.x;
    int tco = tid & 31;    // co = co0 + tco*4 + j
    int tpx = tid >> 5;    // px = tpx*4 + i
    float acc[4][4];
    #pragma unroll
    for (int i=0;i<4;i++)
    #pragma unroll
    for (int j=0;j<4;j++) acc[i][j] = 0.f;

    for (int kh=0; kh<3; kh++){
        int ph = h + kh - 1;
        bool rowok = (ph >= 0 && ph < BEVH);
        for (int kw=0; kw<3; kw++){
            const float* wk = wt + (size_t)(kh*3+kw)*256*256;
            for (int ci0=0; ci0<256; ci0+=32){
                __syncthreads();
                {
                    int ci = tid & 31;
                    for (int i = tid>>5; i < 32; i += 8){
                        int pw = w0 + i + kw - 1;
                        float val = 0.f;
                        if (rowok && pw >= 0 && pw < BEVW)
                            val = aggN[(size_t)(ph*BEVW + pw)*256 + ci0 + ci];
                        in_lds[ci][i] = val;
                    }
                }
                #pragma unroll
                for (int l = 0; l < 16; l++){
                    int e  = l*256 + tid;
                    int ci = e >> 7, co = e & 127;
                    w_lds[e] = wk[(size_t)(ci0+ci)*256 + co0 + co];
                }
                __syncthreads();
                #pragma unroll
                for (int ci=0; ci<32; ci++){
                    float4 wv = *(const float4*)&w_lds[ci*128 + tco*4];
                    float4 iv = *(const float4*)&in_lds[ci][tpx*4];
                    acc[0][0] += iv.x*wv.x; acc[0][1] += iv.x*wv.y; acc[0][2] += iv.x*wv.z; acc[0][3] += iv.x*wv.w;
                    acc[1][0] += iv.y*wv.x; acc[1][1] += iv.y*wv.y; acc[1][2] += iv.y*wv.z; acc[1][3] += iv.y*wv.w;
                    acc[2][0] += iv.z*wv.x; acc[2][1] += iv.z*wv.y; acc[2][2] += iv.z*wv.z; acc[2][3] += iv.z*wv.w;
                    acc[3][0] += iv.w*wv.x; acc[3][1] += iv.w*wv.y; acc[3][2] += iv.w*wv.z; acc[3][3] += iv.w*wv.w;
                }
            }
        }
    }
    #pragma unroll
    for (int j=0;j<4;j++){
        int co = co0 + tco*4 + j;
        float sc = bn_g[co] * rsqrtf(bn_v[co] + 1e-5f);
        float sh = bn_b[co] - bn_m[co]*sc;
        float cb = conv_b[co];
        #pragma unroll
        for (int i=0;i<4;i++){
            int p = h*BEVW + w0 + tpx*4 + i;
            float y = (acc[i][j] + cb)*sc + sh;
            xN[(size_t)p*CCH + co] = fmaxf(y, 0.f);
        }
    }
}

// ---------------- SE ----------------
__global__ void k_zero(float* s){ s[threadIdx.x] = 0.f; }

__global__ __launch_bounds__(256) void k_se_sum(const float* __restrict__ xN, float* __restrict__ ssum){
    int t = threadIdx.x;
    float acc = 0.f;
    int p0 = blockIdx.x * 256;
    for (int p=0; p<256; p++) acc += xN[(size_t)(p0+p)*CCH + t];
    atomicAdd(&ssum[t], acc);
}

__global__ __launch_bounds__(256) void k_se_scale(const float* __restrict__ ssum,
    const float* __restrict__ se_w, const float* __restrict__ se_b, float* __restrict__ scale){
    __shared__ float sm[256];
    int t = threadIdx.x;
    sm[t] = ssum[t] * (1.f/16384.f);
    __syncthreads();
    float acc = se_b[t];
    for (int k=0; k<256; k+=4){
        float4 w4 = *(const float4*)&se_w[(size_t)t*256 + k];
        acc += sm[k]*w4.x + sm[k+1]*w4.y + sm[k+2]*w4.z + sm[k+3]*w4.w;
    }
    scale[t] = sigmoidf_(acc);
}

// ---------------- CBAM maps: per-pixel channel max & mean of x*scale ----------------
__global__ __launch_bounds__(256) void k_maps(const float* __restrict__ xN, const float* __restrict__ scale,
    float* __restrict__ amax, float* __restrict__ amean)
{
    int wid = threadIdx.x >> 6, lane = threadIdx.x & 63;
    int p = blockIdx.x*4 + wid;
    float4 v  = *(const float4*)&xN[(size_t)p*CCH + lane*4];
    float4 sc = *(const float4*)&scale[lane*4];
    float a = v.x*sc.x, b = v.y*sc.y, c = v.z*sc.z, d = v.w*sc.w;
    float mx = fmaxf(fmaxf(a,b), fmaxf(c,d));
    float sm = a+b+c+d;
    #pragma unroll
    for (int off=1; off<64; off<<=1){
        mx = fmaxf(mx, __shfl_xor(mx, off, 64));
        sm += __shfl_xor(sm, off, 64);
    }
    if (lane == 0){ amax[p] = mx; amean[p] = sm*(1.f/256.f); }
}

// ---------------- CBAM 7x7 conv (2->1) + sigmoid ----------------
__global__ __launch_bounds__(256) void k_cbam(const float* __restrict__ amax, const float* __restrict__ amean,
    const float* __restrict__ cw, const float* __restrict__ cb, float* __restrict__ amap)
{
    __shared__ float w[98];
    int t = threadIdx.x;
    if (t < 98) w[t] = cw[t];
    __syncthreads();
    int p = blockIdx.x*256 + t;
    int h = p >> 7, x = p & 127;
    float acc = cb[0];
    for (int kh=0; kh<7; kh++){
        int ph = h + kh - 3;
        if (ph < 0 || ph >= BEVH) continue;
        for (int kw=0; kw<7; kw++){
            int pw = x + kw - 3;
            if (pw < 0 || pw >= BEVW) continue;
            int pp = ph*BEVW + pw;
            acc += amax[pp]*w[kh*7+kw] + amean[pp]*w[49 + kh*7+kw];
        }
    }
    amap[p] = sigmoidf_(acc);
}

// ---------------- final: out[q][c] = x[q][c]*scale[c]*amap[q] ----------------
__global__ __launch_bounds__(256) void k_final(const float* __restrict__ xN, const float* __restrict__ scale,
    const float* __restrict__ amap, float* __restrict__ out)
{
    int idx = blockIdx.x*256 + threadIdx.x;  // float4 granularity
    int p  = idx >> 6;
    int c4 = (idx & 63) * 4;
    float4 v  = *(const float4*)&xN[(size_t)p*CCH + c4];
    float4 sc = *(const float4*)&scale[c4];
    float am = amap[p];
    float4 o;
    o.x = v.x*sc.x*am; o.y = v.y*sc.y*am; o.z = v.z*sc.z*am; o.w = v.w*sc.w*am;
    *(float4*)&out[(size_t)p*CCH + c4] = o;
}

extern "C" void kernel_launch(void* const* d_in, const int* in_sizes, int n_in,
                              void* d_out, int out_size, void* d_ws, size_t ws_size,
                              hipStream_t stream) {
    const float* feat   = (const float*)d_in[0];
    const float* bq     = (const float*)d_in[1];
    const float* bpos   = (const float*)d_in[2];
    const float* refp   = (const float*)d_in[3];
    const float* pcr    = (const float*)d_in[4];
    const float* l2i    = (const float*)d_in[5];
    const float* dpr    = (const float*)d_in[6];
    const float* w_pos  = (const float*)d_in[7];
    const float* b_pos  = (const float*)d_in[8];
    const float* w_img  = (const float*)d_in[9];
    const float* b_img  = (const float*)d_in[10];
    const float* w_att  = (const float*)d_in[11];
    const float* b_att  = (const float*)d_in[12];
    const float* conv_w = (const float*)d_in[13];
    const float* conv_b = (const float*)d_in[14];
    const float* bn_g   = (const float*)d_in[15];
    const float* bn_b   = (const float*)d_in[16];
    const float* bn_m   = (const float*)d_in[17];
    const float* bn_v   = (const float*)d_in[18];
    const float* se_w   = (const float*)d_in[19];
    const float* se_b   = (const float*)d_in[20];
    const float* cbw    = (const float*)d_in[21];
    const float* cbb    = (const float*)d_in[22];
    float* out = (float*)d_out;

    float* ws = (float*)d_ws;
    size_t o = 0;
    float* feat_t  = ws + o;  o += (size_t)6*2816*256;
    float* wt      = ws + o;  o += (size_t)9*256*256;
    int*   tap_off = (int*)(ws + o); o += (size_t)QN*24;
    float* tap_w   = ws + o;  o += (size_t)QN*24;
    float* aggN    = ws + o;  o += (size_t)QN*256;
    float* xN      = ws + o;  o += (size_t)QN*256;
    float* ssum    = ws + o;  o += 256;
    float* scale   = ws + o;  o += 256;
    float* amax    = ws + o;  o += QN;
    float* amean   = ws + o;  o += QN;
    float* amap    = ws + o;  o += QN;

    k_tfeat<<<dim3(88,8,6), 256, 0, stream>>>(feat, feat_t);
    k_wt<<<(9*256*256+255)/256, 256, 0, stream>>>(conv_w, wt);
    k_geom<<<QN/4, 256, 0, stream>>>(bq, bpos, refp, pcr, l2i, dpr,
                                     w_pos, b_pos, w_img, b_img, w_att, b_att,
                                     tap_off, tap_w, out + (size_t)QN*256);
    k_agg<<<QN, 256, 0, stream>>>(feat_t, tap_off, tap_w, aggN);
    k_conv<<<dim3(512,2), 256, 0, stream>>>(aggN, wt, conv_b, bn_g, bn_b, bn_m, bn_v, xN);
    k_zero<<<1, 256, 0, stream>>>(ssum);
    k_se_sum<<<64, 256, 0, stream>>>(xN, ssum);
    k_se_scale<<<1, 256, 0, stream>>>(ssum, se_w, se_b, scale);
    k_maps<<<QN/4, 256, 0, stream>>>(xN, scale, amax, amean);
    k_cbam<<<QN/256, 256, 0, stream>>>(amax, amean, cbw, cbb, amap);
    k_final<<<QN*64/256, 256, 0, stream>>>(xN, scale, amap, out);
}

// Round 2
// 287.666 us; speedup vs baseline: 1.9684x; 1.9684x over previous
//
#include <hip/hip_runtime.h>
#include <math.h>

#define QN   16384
#define CCH  256
#define NCAM 6
#define HFD  32
#define WFD  88
#define DDD  64
#define BEVH 128
#define BEVW 128
#define IMGW 704.0f
#define IMGH 256.0f
#define EPSV 1e-5f

typedef __attribute__((ext_vector_type(8))) short bf8_t;    // 8 bf16
typedef __attribute__((ext_vector_type(8))) unsigned short us8;
typedef __attribute__((ext_vector_type(4))) float f4_t;

__device__ __forceinline__ float sigmoidf_(float x){ return 1.0f/(1.0f+__expf(-x)); }

__device__ __forceinline__ unsigned short f2bf(float f){
    unsigned int b = __float_as_uint(f);
    b += 0x7FFFu + ((b >> 16) & 1u);
    return (unsigned short)(b >> 16);
}

// ---------------- feat transpose: (6,256,32,88) -> (6, 32*88, 256) NHWC ----------------
__global__ __launch_bounds__(256) void k_tfeat(const float* __restrict__ feat, float* __restrict__ feat_t){
    __shared__ float tile[32][33];
    int n  = blockIdx.z;
    int pb = blockIdx.x * 32;   // over 2816 pixels
    int cb = blockIdx.y * 32;   // over 256 channels
    int tx = threadIdx.x & 31, ty = threadIdx.x >> 5;
    for (int r = ty; r < 32; r += 8)
        tile[r][tx] = feat[(size_t)(n*256 + cb + r)*2816 + pb + tx];
    __syncthreads();
    for (int r = ty; r < 32; r += 8)
        feat_t[(size_t)(n*2816 + pb + r)*256 + cb + tx] = tile[tx][r];
}

// ---------------- conv weight: (co,ci,3,3) -> bf16 [kk][co][ci] ----------------
__global__ __launch_bounds__(256) void k_wt(const float* __restrict__ cw, unsigned short* __restrict__ wtH){
    int idx = blockIdx.x*256 + threadIdx.x;
    if (idx >= 9*256*256) return;
    int ci = idx & 255;
    int co = (idx >> 8) & 255;
    int kk = idx >> 16;
    wtH[idx] = f2bf(cw[(size_t)(co*256 + ci)*9 + kk]);
}

// ---------------- per-query geometry: taps + rp ----------------
__global__ __launch_bounds__(256) void k_geom(
    const float* __restrict__ bq, const float* __restrict__ bpos,
    const float* __restrict__ refp, const float* __restrict__ pcr,
    const float* __restrict__ l2i, const float* __restrict__ dpr,
    const float* __restrict__ w_pos, const float* __restrict__ b_pos,
    const float* __restrict__ w_img, const float* __restrict__ b_img,
    const float* __restrict__ w_att, const float* __restrict__ b_att,
    int* __restrict__ tap_off, float* __restrict__ tap_w,
    float* __restrict__ out_rp)
{
    int wave = (blockIdx.x * blockDim.x + threadIdx.x) >> 6;
    int lane = threadIdx.x & 63;
    int q = wave;
    int c0 = lane * 4;

    const float4 a4 = *(const float4*)(bq  + (size_t)q*CCH + c0);
    const float4 b4 = *(const float4*)(bpos+ (size_t)q*CCH + c0);
    float qv[4] = {a4.x+b4.x, a4.y+b4.y, a4.z+b4.z, a4.w+b4.w};

    float s[19];   // 0: pos, 1..6: att, 7..18: img
    {
        const float4 wp = *(const float4*)(w_pos + c0);
        s[0] = qv[0]*wp.x + qv[1]*wp.y + qv[2]*wp.z + qv[3]*wp.w;
    }
    #pragma unroll
    for (int j=0;j<6;j++){
        float a = 0.f;
        #pragma unroll
        for (int k=0;k<4;k++) a += qv[k]*w_att[(c0+k)*6 + j];
        s[1+j] = a;
    }
    #pragma unroll
    for (int j=0;j<12;j++){
        float a = 0.f;
        #pragma unroll
        for (int k=0;k<4;k++) a += qv[k]*w_img[(c0+k)*12 + j];
        s[7+j] = a;
    }
    #pragma unroll
    for (int off=1; off<64; off<<=1){
        #pragma unroll
        for (int i=0;i<19;i++) s[i] += __shfl_xor(s[i], off, 64);
    }

    float pos_off = s[0] + b_pos[0];
    float rx = refp[q*3+0], ry = refp[q*3+1], rz = refp[q*3+2];
    float zc_ = fminf(fmaxf(rz, 0.f), 1.f);
    float inv = logf(fmaxf(zc_, EPSV) / fmaxf(1.f - zc_, EPSV));
    float znew = sigmoidf_(inv + pos_off);

    if (lane == 0){
        out_rp[q*3+0] = rx; out_rp[q*3+1] = ry; out_rp[q*3+2] = znew;
    }
    if (lane < NCAM){
        int n = lane;
        float att  = s[1+n] + b_att[n];
        float offx = (s[7+2*n]   + b_img[2*n])   / (float)WFD;
        float offy = (s[7+2*n+1] + b_img[2*n+1]) / (float)HFD;
        float lo0=pcr[0], lo1=pcr[1], lo2=pcr[2];
        float hi0=pcr[3], hi1=pcr[4], hi2=pcr[5];
        float px = rx*(hi0-lo0)+lo0, py = ry*(hi1-lo1)+lo1, pz = znew*(hi2-lo2)+lo2;
        const float* M = l2i + n*16;
        float cx = M[0]*px + M[1]*py + M[2]*pz  + M[3];
        float cy = M[4]*px + M[5]*py + M[6]*pz  + M[7];
        float cz = M[8]*px + M[9]*py + M[10]*pz + M[11];
        bool m = cz > EPSV;
        float zdiv = fmaxf(cz, EPSV);
        float u = (cx/zdiv)/IMGW; u = (u - 0.5f)*2.f;
        float v = (cy/zdiv)/IMGH; v = (v - 0.5f)*2.f;
        m = m && (u > -1.f) && (u < 1.f) && (v > -1.f) && (v < 1.f);
        float rdn = (cz/(float)DDD - 0.5f)*2.f;
        m = m && (rdn > -1.f) && (rdn < 1.f);

        int base = q*24 + n*4;
        float wq = 0.f, xs = 0.f, ys = 0.f;
        if (m){
            float u2 = u + offx, v2 = v + offy;
            xs = (u2 + 1.f)*0.5f*WFD - 0.5f;
            ys = (v2 + 1.f)*0.5f*HFD - 0.5f;
            float zs = (rdn + 1.f)*0.5f*DDD - 0.5f;
            float fx = floorf(xs), fy = floorf(ys), fz = floorf(zs);
            int x0=(int)fx, y0=(int)fy, z0=(int)fz;
            float wx = xs-fx, wy = ys-fy, wz = zs-fz;
            float dp = 0.f;
            const float* vol = dpr + (size_t)n*DDD*HFD*WFD;
            #pragma unroll
            for (int dz=0; dz<2; dz++)
            #pragma unroll
            for (int dy=0; dy<2; dy++)
            #pragma unroll
            for (int dx=0; dx<2; dx++){
                int ix=x0+dx, iy=y0+dy, iz=z0+dz;
                if (ix>=0 && ix<WFD && iy>=0 && iy<HFD && iz>=0 && iz<DDD){
                    float ww = (dx?wx:1.f-wx)*(dy?wy:1.f-wy)*(dz?wz:1.f-wz);
                    dp += ww * vol[(size_t)(iz*HFD+iy)*WFD + ix];
                }
            }
            wq = sigmoidf_(att) * dp;
        }
        if (m && wq != 0.f){
            float fx = floorf(xs), fy = floorf(ys);
            int x0=(int)fx, y0=(int)fy;
            float wx = xs-fx, wy = ys-fy;
            float cwv[4] = {(1.f-wx)*(1.f-wy), wx*(1.f-wy), (1.f-wx)*wy, wx*wy};
            int xi[4] = {x0, x0+1, x0, x0+1};
            int yi[4] = {y0, y0, y0+1, y0+1};
            #pragma unroll
            for (int k=0;k<4;k++){
                bool ok = (xi[k]>=0 && xi[k]<WFD && yi[k]>=0 && yi[k]<HFD);
                tap_off[base+k] = ok ? ((n*HFD + yi[k])*WFD + xi[k]) : 0;
                tap_w[base+k]   = ok ? wq*cwv[k] : 0.f;
            }
        } else {
            #pragma unroll
            for (int k=0;k<4;k++){ tap_off[base+k] = 0; tap_w[base+k] = 0.f; }
        }
    }
}

// ---------------- aggregation: aggH[q][c] = bf16( sum_taps w * feat_t[off][c] ) ----------------
__global__ __launch_bounds__(256) void k_agg(const float* __restrict__ feat_t,
    const int* __restrict__ tap_off, const float* __restrict__ tap_w,
    unsigned short* __restrict__ aggH)
{
    __shared__ int   so[192];
    __shared__ float sw[192];
    int q0 = blockIdx.x * 8;
    int t = threadIdx.x;
    if (t < 192){ so[t] = tap_off[q0*24+t]; sw[t] = tap_w[q0*24+t]; }
    __syncthreads();
    #pragma unroll
    for (int qi=0; qi<8; qi++){
        float acc = 0.f;
        #pragma unroll
        for (int k=0;k<24;k++){
            float w = sw[qi*24+k];
            if (w != 0.f) acc += w * feat_t[(size_t)so[qi*24+k]*CCH + t];
        }
        aggH[(size_t)(q0+qi)*CCH + t] = f2bf(acc);
    }
}

// ---------------- conv3x3 256->256 + bias + BN + ReLU, bf16 MFMA implicit GEMM ----------------
// tile: 64 px (M) x 128 co (N), K = 9*256 staged in 36 chunks of 64 ci
__global__ __launch_bounds__(256) void k_conv_mfma(const unsigned short* __restrict__ aggH,
    const unsigned short* __restrict__ wtH, const float* __restrict__ conv_b,
    const float* __restrict__ bn_g, const float* __restrict__ bn_b,
    const float* __restrict__ bn_m, const float* __restrict__ bn_v,
    float* __restrict__ xN)
{
    __shared__ unsigned short Al[64][72];    // [m][k], +8 pad
    __shared__ unsigned short Bl[128][72];   // [n][k], +8 pad
    int bx  = blockIdx.x;          // 256: h = bx>>1, w0 = (bx&1)*64
    int h   = bx >> 1;
    int w0  = (bx & 1) * 64;
    int co0 = blockIdx.y * 128;
    int tid  = threadIdx.x;
    int lane = tid & 63, wid = tid >> 6;
    int m_base = (wid >> 1) * 32;
    int n_base = (wid & 1) * 64;
    int l15 = lane & 15, quad = lane >> 4;

    f4_t acc[2][4];
    #pragma unroll
    for (int i=0;i<2;i++)
    #pragma unroll
    for (int j=0;j<4;j++) acc[i][j] = (f4_t){0.f,0.f,0.f,0.f};

    int ar = tid >> 2;            // A stage: m row 0..63
    int as = (tid & 3) * 16;      // ci segment
    int br = tid >> 1;            // B stage: n row 0..127
    int bs = (tid & 1) * 32;

    for (int kk=0; kk<9; kk++){
        int kh = kk / 3, kw = kk - kh*3;
        int ph = h + kh - 1;
        int pw = w0 + ar + kw - 1;
        bool aok = (ph >= 0 && ph < BEVH && pw >= 0 && pw < BEVW);
        const unsigned short* asrc = aggH + ((size_t)(ph*BEVW + pw)*CCH) + as;
        const unsigned short* bsrc = wtH + ((size_t)(kk*256 + co0 + br)*256) + bs;
        for (int ci0=0; ci0<256; ci0+=64){
            __syncthreads();
            if (aok){
                *(us8*)&Al[ar][as]     = *(const us8*)(asrc + ci0);
                *(us8*)&Al[ar][as+8]   = *(const us8*)(asrc + ci0 + 8);
            } else {
                us8 z = (us8){0,0,0,0,0,0,0,0};
                *(us8*)&Al[ar][as]   = z;
                *(us8*)&Al[ar][as+8] = z;
            }
            *(us8*)&Bl[br][bs]      = *(const us8*)(bsrc + ci0);
            *(us8*)&Bl[br][bs+8]    = *(const us8*)(bsrc + ci0 + 8);
            *(us8*)&Bl[br][bs+16]   = *(const us8*)(bsrc + ci0 + 16);
            *(us8*)&Bl[br][bs+24]   = *(const us8*)(bsrc + ci0 + 24);
            __syncthreads();
            #pragma unroll
            for (int ko=0; ko<64; ko+=32){
                bf8_t a0 = *(bf8_t*)&Al[m_base      + l15][ko + quad*8];
                bf8_t a1 = *(bf8_t*)&Al[m_base + 16 + l15][ko + quad*8];
                bf8_t b0 = *(bf8_t*)&Bl[n_base      + l15][ko + quad*8];
                bf8_t b1 = *(bf8_t*)&Bl[n_base + 16 + l15][ko + quad*8];
                bf8_t b2 = *(bf8_t*)&Bl[n_base + 32 + l15][ko + quad*8];
                bf8_t b3 = *(bf8_t*)&Bl[n_base + 48 + l15][ko + quad*8];
                acc[0][0] = __builtin_amdgcn_mfma_f32_16x16x32_bf16(a0, b0, acc[0][0], 0, 0, 0);
                acc[0][1] = __builtin_amdgcn_mfma_f32_16x16x32_bf16(a0, b1, acc[0][1], 0, 0, 0);
                acc[0][2] = __builtin_amdgcn_mfma_f32_16x16x32_bf16(a0, b2, acc[0][2], 0, 0, 0);
                acc[0][3] = __builtin_amdgcn_mfma_f32_16x16x32_bf16(a0, b3, acc[0][3], 0, 0, 0);
                acc[1][0] = __builtin_amdgcn_mfma_f32_16x16x32_bf16(a1, b0, acc[1][0], 0, 0, 0);
                acc[1][1] = __builtin_amdgcn_mfma_f32_16x16x32_bf16(a1, b1, acc[1][1], 0, 0, 0);
                acc[1][2] = __builtin_amdgcn_mfma_f32_16x16x32_bf16(a1, b2, acc[1][2], 0, 0, 0);
                acc[1][3] = __builtin_amdgcn_mfma_f32_16x16x32_bf16(a1, b3, acc[1][3], 0, 0, 0);
            }
        }
    }

    #pragma unroll
    for (int j=0;j<4;j++){
        int co = co0 + n_base + j*16 + l15;
        float sc = bn_g[co] * rsqrtf(bn_v[co] + 1e-5f);
        float sh = bn_b[co] - bn_m[co]*sc;
        float cb = conv_b[co];
        #pragma unroll
        for (int i=0;i<2;i++){
            #pragma unroll
            for (int r=0;r<4;r++){
                int m = m_base + i*16 + quad*4 + r;
                int p = h*BEVW + w0 + m;
                float y = (acc[i][j][r] + cb)*sc + sh;
                xN[(size_t)p*CCH + co] = fmaxf(y, 0.f);
            }
        }
    }
}

// ---------------- SE ----------------
__global__ void k_zero(float* s){ s[threadIdx.x] = 0.f; }

__global__ __launch_bounds__(256) void k_se_sum(const float* __restrict__ xN, float* __restrict__ ssum){
    int t = threadIdx.x;
    float acc = 0.f;
    int p0 = blockIdx.x * 256;
    for (int p=0; p<256; p++) acc += xN[(size_t)(p0+p)*CCH + t];
    atomicAdd(&ssum[t], acc);
}

__global__ __launch_bounds__(256) void k_se_scale(const float* __restrict__ ssum,
    const float* __restrict__ se_w, const float* __restrict__ se_b, float* __restrict__ scale){
    __shared__ float sm[256];
    int t = threadIdx.x;
    sm[t] = ssum[t] * (1.f/16384.f);
    __syncthreads();
    float acc = se_b[t];
    for (int k=0; k<256; k+=4){
        float4 w4 = *(const float4*)&se_w[(size_t)t*256 + k];
        acc += sm[k]*w4.x + sm[k+1]*w4.y + sm[k+2]*w4.z + sm[k+3]*w4.w;
    }
    scale[t] = sigmoidf_(acc);
}

// ---------------- CBAM maps ----------------
__global__ __launch_bounds__(256) void k_maps(const float* __restrict__ xN, const float* __restrict__ scale,
    float* __restrict__ amax, float* __restrict__ amean)
{
    int wid = threadIdx.x >> 6, lane = threadIdx.x & 63;
    int p = blockIdx.x*4 + wid;
    float4 v  = *(const float4*)&xN[(size_t)p*CCH + lane*4];
    float4 sc = *(const float4*)&scale[lane*4];
    float a = v.x*sc.x, b = v.y*sc.y, c = v.z*sc.z, d = v.w*sc.w;
    float mx = fmaxf(fmaxf(a,b), fmaxf(c,d));
    float sm = a+b+c+d;
    #pragma unroll
    for (int off=1; off<64; off<<=1){
        mx = fmaxf(mx, __shfl_xor(mx, off, 64));
        sm += __shfl_xor(sm, off, 64);
    }
    if (lane == 0){ amax[p] = mx; amean[p] = sm*(1.f/256.f); }
}

// ---------------- CBAM 7x7 conv (2->1) + sigmoid ----------------
__global__ __launch_bounds__(256) void k_cbam(const float* __restrict__ amax, const float* __restrict__ amean,
    const float* __restrict__ cw, const float* __restrict__ cb, float* __restrict__ amap)
{
    __shared__ float w[98];
    int t = threadIdx.x;
    if (t < 98) w[t] = cw[t];
    __syncthreads();
    int p = blockIdx.x*256 + t;
    int h = p >> 7, x = p & 127;
    float acc = cb[0];
    for (int kh=0; kh<7; kh++){
        int ph = h + kh - 3;
        if (ph < 0 || ph >= BEVH) continue;
        for (int kw=0; kw<7; kw++){
            int pw = x + kw - 3;
            if (pw < 0 || pw >= BEVW) continue;
            int pp = ph*BEVW + pw;
            acc += amax[pp]*w[kh*7+kw] + amean[pp]*w[49 + kh*7+kw];
        }
    }
    amap[p] = sigmoidf_(acc);
}

// ---------------- final ----------------
__global__ __launch_bounds__(256) void k_final(const float* __restrict__ xN, const float* __restrict__ scale,
    const float* __restrict__ amap, float* __restrict__ out)
{
    int idx = blockIdx.x*256 + threadIdx.x;  // float4 granularity
    int p  = idx >> 6;
    int c4 = (idx & 63) * 4;
    float4 v  = *(const float4*)&xN[(size_t)p*CCH + c4];
    float4 sc = *(const float4*)&scale[c4];
    float am = amap[p];
    float4 o;
    o.x = v.x*sc.x*am; o.y = v.y*sc.y*am; o.z = v.z*sc.z*am; o.w = v.w*sc.w*am;
    *(float4*)&out[(size_t)p*CCH + c4] = o;
}

extern "C" void kernel_launch(void* const* d_in, const int* in_sizes, int n_in,
                              void* d_out, int out_size, void* d_ws, size_t ws_size,
                              hipStream_t stream) {
    const float* feat   = (const float*)d_in[0];
    const float* bq     = (const float*)d_in[1];
    const float* bpos   = (const float*)d_in[2];
    const float* refp   = (const float*)d_in[3];
    const float* pcr    = (const float*)d_in[4];
    const float* l2i    = (const float*)d_in[5];
    const float* dpr    = (const float*)d_in[6];
    const float* w_pos  = (const float*)d_in[7];
    const float* b_pos  = (const float*)d_in[8];
    const float* w_img  = (const float*)d_in[9];
    const float* b_img  = (const float*)d_in[10];
    const float* w_att  = (const float*)d_in[11];
    const float* b_att  = (const float*)d_in[12];
    const float* conv_w = (const float*)d_in[13];
    const float* conv_b = (const float*)d_in[14];
    const float* bn_g   = (const float*)d_in[15];
    const float* bn_b   = (const float*)d_in[16];
    const float* bn_m   = (const float*)d_in[17];
    const float* bn_v   = (const float*)d_in[18];
    const float* se_w   = (const float*)d_in[19];
    const float* se_b   = (const float*)d_in[20];
    const float* cbw    = (const float*)d_in[21];
    const float* cbb    = (const float*)d_in[22];
    float* out = (float*)d_out;

    float* ws = (float*)d_ws;
    size_t o = 0;
    float* feat_t  = ws + o;  o += (size_t)6*2816*256;
    unsigned short* wtH  = (unsigned short*)(ws + o); o += (size_t)9*256*128;   // 9*256*256 ushorts
    int*   tap_off = (int*)(ws + o); o += (size_t)QN*24;
    float* tap_w   = ws + o;  o += (size_t)QN*24;
    unsigned short* aggH = (unsigned short*)(ws + o); o += (size_t)QN*128;      // QN*256 ushorts
    float* xN      = ws + o;  o += (size_t)QN*256;
    float* ssum    = ws + o;  o += 256;
    float* scale   = ws + o;  o += 256;
    float* amax    = ws + o;  o += QN;
    float* amean   = ws + o;  o += QN;
    float* amap    = ws + o;  o += QN;

    k_tfeat<<<dim3(88,8,6), 256, 0, stream>>>(feat, feat_t);
    k_wt<<<(9*256*256+255)/256, 256, 0, stream>>>(conv_w, wtH);
    k_geom<<<QN/4, 256, 0, stream>>>(bq, bpos, refp, pcr, l2i, dpr,
                                     w_pos, b_pos, w_img, b_img, w_att, b_att,
                                     tap_off, tap_w, out + (size_t)QN*256);
    k_agg<<<QN/8, 256, 0, stream>>>(feat_t, tap_off, tap_w, aggH);
    k_conv_mfma<<<dim3(256,2), 256, 0, stream>>>(aggH, wtH, conv_b, bn_g, bn_b, bn_m, bn_v, xN);
    k_zero<<<1, 256, 0, stream>>>(ssum);
    k_se_sum<<<64, 256, 0, stream>>>(xN, ssum);
    k_se_scale<<<1, 256, 0, stream>>>(ssum, se_w, se_b, scale);
    k_maps<<<QN/4, 256, 0, stream>>>(xN, scale, amax, amean);
    k_cbam<<<QN/256, 256, 0, stream>>>(amax, amean, cbw, cbb, amap);
    k_final<<<QN*64/256, 256, 0, stream>>>(xN, scale, amap, out);
}

// Round 3
// 264.299 us; speedup vs baseline: 2.1424x; 1.0884x over previous
//
#include <hip/hip_runtime.h>
#include <math.h>

#define QN   16384
#define CCH  256
#define NCAM 6
#define HFD  32
#define WFD  88
#define DDD  64
#define BEVH 128
#define BEVW 128
#define IMGW 704.0f
#define IMGH 256.0f
#define EPSV 1e-5f

typedef __attribute__((ext_vector_type(8))) short bf8_t;    // 8 bf16 (MFMA operand)
typedef __attribute__((ext_vector_type(8))) unsigned short us8;
typedef __attribute__((ext_vector_type(4))) unsigned short us4;
typedef __attribute__((ext_vector_type(4))) float f4_t;

__device__ __forceinline__ float sigmoidf_(float x){ return 1.0f/(1.0f+__expf(-x)); }

__device__ __forceinline__ unsigned short f2bf(float f){
    unsigned int b = __float_as_uint(f);
    b += 0x7FFFu + ((b >> 16) & 1u);
    return (unsigned short)(b >> 16);
}
__device__ __forceinline__ float bf2f(unsigned short u){
    return __uint_as_float(((unsigned int)u) << 16);
}

// ---------------- feat transpose: (6,256,32,88) f32 -> (6, 32*88, 256) bf16 NHWC ----------------
__global__ __launch_bounds__(256) void k_tfeat(const float* __restrict__ feat, unsigned short* __restrict__ feat_tH){
    __shared__ float tile[32][33];
    int n  = blockIdx.z;
    int pb = blockIdx.x * 32;   // over 2816 pixels
    int cb = blockIdx.y * 32;   // over 256 channels
    int tx = threadIdx.x & 31, ty = threadIdx.x >> 5;
    for (int r = ty; r < 32; r += 8)
        tile[r][tx] = feat[(size_t)(n*256 + cb + r)*2816 + pb + tx];
    __syncthreads();
    for (int r = ty; r < 32; r += 8)
        feat_tH[(size_t)(n*2816 + pb + r)*256 + cb + tx] = f2bf(tile[tx][r]);
}

// ---------------- conv weight: (co,ci,3,3) -> bf16 [kk][co][ci]; also zero ssum ----------------
__global__ __launch_bounds__(256) void k_wt(const float* __restrict__ cw, unsigned short* __restrict__ wtH,
                                            float* __restrict__ ssum){
    if (blockIdx.x == 0) ssum[threadIdx.x] = 0.f;
    int idx = blockIdx.x*256 + threadIdx.x;
    if (idx >= 9*256*256) return;
    int ci = idx & 255;
    int co = (idx >> 8) & 255;
    int kk = idx >> 16;
    wtH[idx] = f2bf(cw[(size_t)(co*256 + ci)*9 + kk]);
}

// ---------------- per-query geometry: taps + rp ----------------
__global__ __launch_bounds__(256) void k_geom(
    const float* __restrict__ bq, const float* __restrict__ bpos,
    const float* __restrict__ refp, const float* __restrict__ pcr,
    const float* __restrict__ l2i, const float* __restrict__ dpr,
    const float* __restrict__ w_pos, const float* __restrict__ b_pos,
    const float* __restrict__ w_img, const float* __restrict__ b_img,
    const float* __restrict__ w_att, const float* __restrict__ b_att,
    int* __restrict__ tap_off, float* __restrict__ tap_w,
    float* __restrict__ out_rp)
{
    int wave = (blockIdx.x * blockDim.x + threadIdx.x) >> 6;
    int lane = threadIdx.x & 63;
    int q = wave;
    int c0 = lane * 4;

    const float4 a4 = *(const float4*)(bq  + (size_t)q*CCH + c0);
    const float4 b4 = *(const float4*)(bpos+ (size_t)q*CCH + c0);
    float qv[4] = {a4.x+b4.x, a4.y+b4.y, a4.z+b4.z, a4.w+b4.w};

    float s[19];   // 0: pos, 1..6: att, 7..18: img
    {
        const float4 wp = *(const float4*)(w_pos + c0);
        s[0] = qv[0]*wp.x + qv[1]*wp.y + qv[2]*wp.z + qv[3]*wp.w;
    }
    #pragma unroll
    for (int j=0;j<6;j++){
        float a = 0.f;
        #pragma unroll
        for (int k=0;k<4;k++) a += qv[k]*w_att[(c0+k)*6 + j];
        s[1+j] = a;
    }
    #pragma unroll
    for (int j=0;j<12;j++){
        float a = 0.f;
        #pragma unroll
        for (int k=0;k<4;k++) a += qv[k]*w_img[(c0+k)*12 + j];
        s[7+j] = a;
    }
    #pragma unroll
    for (int off=1; off<64; off<<=1){
        #pragma unroll
        for (int i=0;i<19;i++) s[i] += __shfl_xor(s[i], off, 64);
    }

    float pos_off = s[0] + b_pos[0];
    float rx = refp[q*3+0], ry = refp[q*3+1], rz = refp[q*3+2];
    float zc_ = fminf(fmaxf(rz, 0.f), 1.f);
    float inv = logf(fmaxf(zc_, EPSV) / fmaxf(1.f - zc_, EPSV));
    float znew = sigmoidf_(inv + pos_off);

    if (lane == 0){
        out_rp[q*3+0] = rx; out_rp[q*3+1] = ry; out_rp[q*3+2] = znew;
    }
    if (lane < NCAM){
        int n = lane;
        float att  = s[1+n] + b_att[n];
        float offx = (s[7+2*n]   + b_img[2*n])   / (float)WFD;
        float offy = (s[7+2*n+1] + b_img[2*n+1]) / (float)HFD;
        float lo0=pcr[0], lo1=pcr[1], lo2=pcr[2];
        float hi0=pcr[3], hi1=pcr[4], hi2=pcr[5];
        float px = rx*(hi0-lo0)+lo0, py = ry*(hi1-lo1)+lo1, pz = znew*(hi2-lo2)+lo2;
        const float* M = l2i + n*16;
        float cx = M[0]*px + M[1]*py + M[2]*pz  + M[3];
        float cy = M[4]*px + M[5]*py + M[6]*pz  + M[7];
        float cz = M[8]*px + M[9]*py + M[10]*pz + M[11];
        bool m = cz > EPSV;
        float zdiv = fmaxf(cz, EPSV);
        float u = (cx/zdiv)/IMGW; u = (u - 0.5f)*2.f;
        float v = (cy/zdiv)/IMGH; v = (v - 0.5f)*2.f;
        m = m && (u > -1.f) && (u < 1.f) && (v > -1.f) && (v < 1.f);
        float rdn = (cz/(float)DDD - 0.5f)*2.f;
        m = m && (rdn > -1.f) && (rdn < 1.f);

        int base = q*24 + n*4;
        float wq = 0.f, xs = 0.f, ys = 0.f;
        if (m){
            float u2 = u + offx, v2 = v + offy;
            xs = (u2 + 1.f)*0.5f*WFD - 0.5f;
            ys = (v2 + 1.f)*0.5f*HFD - 0.5f;
            float zs = (rdn + 1.f)*0.5f*DDD - 0.5f;
            float fx = floorf(xs), fy = floorf(ys), fz = floorf(zs);
            int x0=(int)fx, y0=(int)fy, z0=(int)fz;
            float wx = xs-fx, wy = ys-fy, wz = zs-fz;
            float dp = 0.f;
            const float* vol = dpr + (size_t)n*DDD*HFD*WFD;
            #pragma unroll
            for (int dz=0; dz<2; dz++)
            #pragma unroll
            for (int dy=0; dy<2; dy++)
            #pragma unroll
            for (int dx=0; dx<2; dx++){
                int ix=x0+dx, iy=y0+dy, iz=z0+dz;
                if (ix>=0 && ix<WFD && iy>=0 && iy<HFD && iz>=0 && iz<DDD){
                    float ww = (dx?wx:1.f-wx)*(dy?wy:1.f-wy)*(dz?wz:1.f-wz);
                    dp += ww * vol[(size_t)(iz*HFD+iy)*WFD + ix];
                }
            }
            wq = sigmoidf_(att) * dp;
        }
        if (m && wq != 0.f){
            float fx = floorf(xs), fy = floorf(ys);
            int x0=(int)fx, y0=(int)fy;
            float wx = xs-fx, wy = ys-fy;
            float cwv[4] = {(1.f-wx)*(1.f-wy), wx*(1.f-wy), (1.f-wx)*wy, wx*wy};
            int xi[4] = {x0, x0+1, x0, x0+1};
            int yi[4] = {y0, y0, y0+1, y0+1};
            #pragma unroll
            for (int k=0;k<4;k++){
                bool ok = (xi[k]>=0 && xi[k]<WFD && yi[k]>=0 && yi[k]<HFD);
                tap_off[base+k] = ok ? ((n*HFD + yi[k])*WFD + xi[k]) : 0;
                tap_w[base+k]   = ok ? wq*cwv[k] : 0.f;
            }
        } else {
            #pragma unroll
            for (int k=0;k<4;k++){ tap_off[base+k] = 0; tap_w[base+k] = 0.f; }
        }
    }
}

// ---------------- aggregation: aggH[q][c] = bf16( sum_taps w * feat_tH[off][c] ) ----------------
// block = 4 waves; each wave owns 2 queries; lane covers 4 channels (us4, 8B/lane)
__global__ __launch_bounds__(256) void k_agg(const unsigned short* __restrict__ feat_tH,
    const int* __restrict__ tap_off, const float* __restrict__ tap_w,
    unsigned short* __restrict__ aggH)
{
    __shared__ int   so[192];
    __shared__ float sw[192];
    int q0 = blockIdx.x * 8;
    int t = threadIdx.x;
    if (t < 192){ so[t] = tap_off[q0*24+t]; sw[t] = tap_w[q0*24+t]; }
    __syncthreads();
    int wid = t >> 6, lane = t & 63;
    int c4 = lane * 4;
    #pragma unroll
    for (int qi=0; qi<2; qi++){
        int ql = wid*2 + qi;
        float a0=0.f, a1=0.f, a2=0.f, a3=0.f;
        #pragma unroll
        for (int k=0;k<24;k++){
            float w = sw[ql*24+k];
            if (w != 0.f){
                us4 v = *(const us4*)(feat_tH + (size_t)so[ql*24+k]*CCH + c4);
                a0 += w * bf2f(v.x);
                a1 += w * bf2f(v.y);
                a2 += w * bf2f(v.z);
                a3 += w * bf2f(v.w);
            }
        }
        us4 o; o.x = f2bf(a0); o.y = f2bf(a1); o.z = f2bf(a2); o.w = f2bf(a3);
        *(us4*)(aggH + (size_t)(q0+ql)*CCH + c4) = o;
    }
}

// ---------------- conv3x3 256->256 + bias + BN + ReLU, bf16 MFMA implicit GEMM ----------------
// tile: 64 px (M) x 64 co (N), K = 9*256 in 36 chunks of 64 ci, register-prefetch pipeline
__global__ __launch_bounds__(256) void k_conv_mfma(const unsigned short* __restrict__ aggH,
    const unsigned short* __restrict__ wtH, const float* __restrict__ conv_b,
    const float* __restrict__ bn_g, const float* __restrict__ bn_b,
    const float* __restrict__ bn_m, const float* __restrict__ bn_v,
    float* __restrict__ xN)
{
    __shared__ unsigned short Al[64][72];    // [m][k], +8 pad
    __shared__ unsigned short Bl[64][72];    // [n][k], +8 pad
    int strip = blockIdx.x;        // 0..255: h = strip>>1, w0 = (strip&1)*64
    int h   = strip >> 1;
    int w0  = (strip & 1) * 64;
    int co0 = blockIdx.y * 64;
    int tid  = threadIdx.x;
    int lane = tid & 63, wid = tid >> 6;
    int mhalf = (wid >> 1) * 32;
    int nhalf = (wid & 1) * 32;
    int l15 = lane & 15, quad = lane >> 4;

    f4_t acc[2][2];
    #pragma unroll
    for (int i=0;i<2;i++)
    #pragma unroll
    for (int j=0;j<2;j++) acc[i][j] = (f4_t){0.f,0.f,0.f,0.f};

    int ar = tid >> 2;            // row 0..63 (m for A, co for B)
    int ac = (tid & 3) * 16;      // ci segment start
    us8 ra0, ra1, rb0, rb1;
    const us8 z8 = (us8){0,0,0,0,0,0,0,0};

    // stage s in [0,36): kk = s>>2, ci0 = (s&3)*64
    #define LOADSTAGE(s) { \
        int kk_ = (s) >> 2; int ci0_ = ((s) & 3) << 6; \
        int kh_ = kk_ / 3, kw_ = kk_ - kh_*3; \
        int ph_ = h + kh_ - 1; \
        int pw_ = w0 + ar + kw_ - 1; \
        if (ph_ >= 0 && ph_ < BEVH && pw_ >= 0 && pw_ < BEVW){ \
            const unsigned short* ap_ = aggH + ((size_t)(ph_*BEVW + pw_)*CCH + ci0_ + ac); \
            ra0 = *(const us8*)ap_; ra1 = *(const us8*)(ap_ + 8); \
        } else { ra0 = z8; ra1 = z8; } \
        const unsigned short* bp_ = wtH + ((size_t)(kk_*256 + co0 + ar)*CCH + ci0_ + ac); \
        rb0 = *(const us8*)bp_; rb1 = *(const us8*)(bp_ + 8); \
    }

    LOADSTAGE(0);
    for (int s=0; s<36; s++){
        __syncthreads();
        *(us8*)&Al[ar][ac]   = ra0;
        *(us8*)&Al[ar][ac+8] = ra1;
        *(us8*)&Bl[ar][ac]   = rb0;
        *(us8*)&Bl[ar][ac+8] = rb1;
        __syncthreads();
        if (s < 35) LOADSTAGE(s+1);
        #pragma unroll
        for (int ko=0; ko<2; ko++){
            bf8_t af0 = *(bf8_t*)&Al[mhalf      + l15][ko*32 + quad*8];
            bf8_t af1 = *(bf8_t*)&Al[mhalf + 16 + l15][ko*32 + quad*8];
            bf8_t bf0 = *(bf8_t*)&Bl[nhalf      + l15][ko*32 + quad*8];
            bf8_t bf1 = *(bf8_t*)&Bl[nhalf + 16 + l15][ko*32 + quad*8];
            acc[0][0] = __builtin_amdgcn_mfma_f32_16x16x32_bf16(af0, bf0, acc[0][0], 0, 0, 0);
            acc[0][1] = __builtin_amdgcn_mfma_f32_16x16x32_bf16(af0, bf1, acc[0][1], 0, 0, 0);
            acc[1][0] = __builtin_amdgcn_mfma_f32_16x16x32_bf16(af1, bf0, acc[1][0], 0, 0, 0);
            acc[1][1] = __builtin_amdgcn_mfma_f32_16x16x32_bf16(af1, bf1, acc[1][1], 0, 0, 0);
        }
    }
    #undef LOADSTAGE

    #pragma unroll
    for (int j=0;j<2;j++){
        int co = co0 + nhalf + j*16 + l15;
        float sc = bn_g[co] * rsqrtf(bn_v[co] + 1e-5f);
        float sh = bn_b[co] - bn_m[co]*sc;
        float cb = conv_b[co];
        #pragma unroll
        for (int i=0;i<2;i++){
            #pragma unroll
            for (int r=0;r<4;r++){
                int m = mhalf + i*16 + quad*4 + r;
                int p = h*BEVW + w0 + m;
                float y = (acc[i][j][r] + cb)*sc + sh;
                xN[(size_t)p*CCH + co] = fmaxf(y, 0.f);
            }
        }
    }
}

// ---------------- SE ----------------
__global__ __launch_bounds__(256) void k_se_sum(const float* __restrict__ xN, float* __restrict__ ssum){
    int t = threadIdx.x;
    float acc = 0.f;
    int p0 = blockIdx.x * 256;
    for (int p=0; p<256; p++) acc += xN[(size_t)(p0+p)*CCH + t];
    atomicAdd(&ssum[t], acc);
}

__global__ __launch_bounds__(256) void k_se_scale(const float* __restrict__ ssum,
    const float* __restrict__ se_w, const float* __restrict__ se_b, float* __restrict__ scale){
    __shared__ float sm[256];
    int t = threadIdx.x;
    sm[t] = ssum[t] * (1.f/16384.f);
    __syncthreads();
    float acc = se_b[t];
    for (int k=0; k<256; k+=4){
        float4 w4 = *(const float4*)&se_w[(size_t)t*256 + k];
        acc += sm[k]*w4.x + sm[k+1]*w4.y + sm[k+2]*w4.z + sm[k+3]*w4.w;
    }
    scale[t] = sigmoidf_(acc);
}

// ---------------- CBAM maps ----------------
__global__ __launch_bounds__(256) void k_maps(const float* __restrict__ xN, const float* __restrict__ scale,
    float* __restrict__ amax, float* __restrict__ amean)
{
    int wid = threadIdx.x >> 6, lane = threadIdx.x & 63;
    int p = blockIdx.x*4 + wid;
    float4 v  = *(const float4*)&xN[(size_t)p*CCH + lane*4];
    float4 sc = *(const float4*)&scale[lane*4];
    float a = v.x*sc.x, b = v.y*sc.y, c = v.z*sc.z, d = v.w*sc.w;
    float mx = fmaxf(fmaxf(a,b), fmaxf(c,d));
    float sm = a+b+c+d;
    #pragma unroll
    for (int off=1; off<64; off<<=1){
        mx = fmaxf(mx, __shfl_xor(mx, off, 64));
        sm += __shfl_xor(sm, off, 64);
    }
    if (lane == 0){ amax[p] = mx; amean[p] = sm*(1.f/256.f); }
}

// ---------------- CBAM 7x7 conv (2->1) + sigmoid ----------------
__global__ __launch_bounds__(256) void k_cbam(const float* __restrict__ amax, const float* __restrict__ amean,
    const float* __restrict__ cw, const float* __restrict__ cb, float* __restrict__ amap)
{
    __shared__ float w[98];
    int t = threadIdx.x;
    if (t < 98) w[t] = cw[t];
    __syncthreads();
    int p = blockIdx.x*256 + t;
    int h = p >> 7, x = p & 127;
    float acc = cb[0];
    for (int kh=0; kh<7; kh++){
        int ph = h + kh - 3;
        if (ph < 0 || ph >= BEVH) continue;
        for (int kw=0; kw<7; kw++){
            int pw = x + kw - 3;
            if (pw < 0 || pw >= BEVW) continue;
            int pp = ph*BEVW + pw;
            acc += amax[pp]*w[kh*7+kw] + amean[pp]*w[49 + kh*7+kw];
        }
    }
    amap[p] = sigmoidf_(acc);
}

// ---------------- final ----------------
__global__ __launch_bounds__(256) void k_final(const float* __restrict__ xN, const float* __restrict__ scale,
    const float* __restrict__ amap, float* __restrict__ out)
{
    int idx = blockIdx.x*256 + threadIdx.x;  // float4 granularity
    int p  = idx >> 6;
    int c4 = (idx & 63) * 4;
    float4 v  = *(const float4*)&xN[(size_t)p*CCH + c4];
    float4 sc = *(const float4*)&scale[c4];
    float am = amap[p];
    float4 o;
    o.x = v.x*sc.x*am; o.y = v.y*sc.y*am; o.z = v.z*sc.z*am; o.w = v.w*sc.w*am;
    *(float4*)&out[(size_t)p*CCH + c4] = o;
}

extern "C" void kernel_launch(void* const* d_in, const int* in_sizes, int n_in,
                              void* d_out, int out_size, void* d_ws, size_t ws_size,
                              hipStream_t stream) {
    const float* feat   = (const float*)d_in[0];
    const float* bq     = (const float*)d_in[1];
    const float* bpos   = (const float*)d_in[2];
    const float* refp   = (const float*)d_in[3];
    const float* pcr    = (const float*)d_in[4];
    const float* l2i    = (const float*)d_in[5];
    const float* dpr    = (const float*)d_in[6];
    const float* w_pos  = (const float*)d_in[7];
    const float* b_pos  = (const float*)d_in[8];
    const float* w_img  = (const float*)d_in[9];
    const float* b_img  = (const float*)d_in[10];
    const float* w_att  = (const float*)d_in[11];
    const float* b_att  = (const float*)d_in[12];
    const float* conv_w = (const float*)d_in[13];
    const float* conv_b = (const float*)d_in[14];
    const float* bn_g   = (const float*)d_in[15];
    const float* bn_b   = (const float*)d_in[16];
    const float* bn_m   = (const float*)d_in[17];
    const float* bn_v   = (const float*)d_in[18];
    const float* se_w   = (const float*)d_in[19];
    const float* se_b   = (const float*)d_in[20];
    const float* cbw    = (const float*)d_in[21];
    const float* cbb    = (const float*)d_in[22];
    float* out = (float*)d_out;

    float* ws = (float*)d_ws;
    size_t o = 0;
    unsigned short* feat_tH = (unsigned short*)(ws + o); o += (size_t)6*2816*128;  // 6*2816*256 ushorts
    unsigned short* wtH  = (unsigned short*)(ws + o); o += (size_t)9*256*128;      // 9*256*256 ushorts
    int*   tap_off = (int*)(ws + o); o += (size_t)QN*24;
    float* tap_w   = ws + o;  o += (size_t)QN*24;
    unsigned short* aggH = (unsigned short*)(ws + o); o += (size_t)QN*128;         // QN*256 ushorts
    float* xN      = ws + o;  o += (size_t)QN*256;
    float* ssum    = ws + o;  o += 256;
    float* scale   = ws + o;  o += 256;
    float* amax    = ws + o;  o += QN;
    float* amean   = ws + o;  o += QN;
    float* amap    = ws + o;  o += QN;

    k_tfeat<<<dim3(88,8,6), 256, 0, stream>>>(feat, feat_tH);
    k_wt<<<(9*256*256+255)/256, 256, 0, stream>>>(conv_w, wtH, ssum);
    k_geom<<<QN/4, 256, 0, stream>>>(bq, bpos, refp, pcr, l2i, dpr,
                                     w_pos, b_pos, w_img, b_img, w_att, b_att,
                                     tap_off, tap_w, out + (size_t)QN*256);
    k_agg<<<QN/8, 256, 0, stream>>>(feat_tH, tap_off, tap_w, aggH);
    k_conv_mfma<<<dim3(256,4), 256, 0, stream>>>(aggH, wtH, conv_b, bn_g, bn_b, bn_m, bn_v, xN);
    k_se_sum<<<64, 256, 0, stream>>>(xN, ssum);
    k_se_scale<<<1, 256, 0, stream>>>(ssum, se_w, se_b, scale);
    k_maps<<<QN/4, 256, 0, stream>>>(xN, scale, amax, amean);
    k_cbam<<<QN/256, 256, 0, stream>>>(amax, amean, cbw, cbb, amap);
    k_final<<<QN*64/256, 256, 0, stream>>>(xN, scale, amap, out);
}